// Round 8
// baseline (190.050 us; speedup 1.0000x reference)
//
#include <hip/hip_runtime.h>
#include <hip/hip_bf16.h>
#include <stdint.h>

#define SEQ    2048
#define BATCH  2
#define DMODEL 1024
#define NHEADS 16
#define HDIM   64
#define MROWS  (BATCH*SEQ)   // 4096

typedef __attribute__((ext_vector_type(8))) short bf16x8;
typedef __attribute__((ext_vector_type(4))) short bf16x4;
typedef __attribute__((ext_vector_type(4))) float f32x4;

__device__ inline void global_to_lds16(const void* g, void* l) {
  __builtin_amdgcn_global_load_lds(
      (const __attribute__((address_space(1))) uint32_t*)g,
      (__attribute__((address_space(3))) uint32_t*)l, 16, 0, 0);
}

__device__ inline unsigned short f2bf_bits(float f) {
  __hip_bfloat16 h = __float2bfloat16(f);
  return *(unsigned short*)&h;
}

// ---------------- x -> bf16 ----------------
__global__ void cvt_x(const float* __restrict__ x, __hip_bfloat16* __restrict__ xb) {
  int i = (blockIdx.x * 256 + threadIdx.x) * 4;
  float4 v = *(const float4*)(x + i);
  ushort4 o;
  o.x = f2bf_bits(v.x); o.y = f2bf_bits(v.y);
  o.z = f2bf_bits(v.z); o.w = f2bf_bits(v.w);
  *(ushort4*)(xb + i) = o;
}

// ------- W [k][n] f32 -> Wt [n][k] bf16 (tiled transpose) -------
__global__ void trans_w(const float* __restrict__ Wq, const float* __restrict__ Wk,
                        const float* __restrict__ Wv, const float* __restrict__ Wo,
                        __hip_bfloat16* __restrict__ Wqkv_t, __hip_bfloat16* __restrict__ Wo_t) {
  __shared__ float tile[32][33];
  int z = blockIdx.z;
  const float* W = (z == 0) ? Wq : (z == 1) ? Wk : (z == 2) ? Wv : Wo;
  __hip_bfloat16* dst = (z < 3) ? (Wqkv_t + (size_t)z * 1024 * 1024) : Wo_t;
  int k0 = blockIdx.x * 32, n0 = blockIdx.y * 32;
  int tx = threadIdx.x & 31, ty = threadIdx.x >> 5;
#pragma unroll
  for (int r = 0; r < 4; r++)
    tile[ty + r * 8][tx] = W[(size_t)(k0 + ty + r * 8) * 1024 + n0 + tx];
  __syncthreads();
#pragma unroll
  for (int r = 0; r < 4; r++)
    dst[(size_t)(n0 + ty + r * 8) * 1024 + k0 + tx] = __float2bfloat16(tile[tx][ty + r * 8]);
}

// ------- V slice of QKV -> Vt[bh][d=64][s=2048] bf16 -------
__global__ void trans_v(const __hip_bfloat16* __restrict__ QKV, __hip_bfloat16* __restrict__ Vt) {
  __shared__ __hip_bfloat16 tile[64][72];
  int bh = blockIdx.y;
  int b = bh >> 4, h = bh & 15;
  int s0 = blockIdx.x * 64;
  int t = threadIdx.x;
  int r = t >> 2, cg = (t & 3) * 16;
  const __hip_bfloat16* src = QKV + ((size_t)(b * SEQ + s0 + r)) * 3072 + 2048 + h * 64 + cg;
  *(uint4*)&tile[r][cg]     = *(const uint4*)src;
  *(uint4*)&tile[r][cg + 8] = *(const uint4*)(src + 8);
  __syncthreads();
  unsigned short tmp[16];
#pragma unroll
  for (int i = 0; i < 16; i++) tmp[i] = *(const unsigned short*)&tile[cg + i][r];
  __hip_bfloat16* dst = Vt + ((size_t)bh * 64 + r) * 2048 + s0 + cg;
  *(uint4*)dst       = *(const uint4*)&tmp[0];
  *(uint4*)(dst + 8) = *(const uint4*)&tmp[8];
}

// ------ GEMM: C[M][ldc] = A[M][1024]*Wt[N][1024]^T (+bias), BK=64, swizzled LDS ------
template <int TN, bool OUT_BF16, int MINW>
__global__ __launch_bounds__(256, MINW)
void gemm_kernel(const __hip_bfloat16* __restrict__ A, const __hip_bfloat16* __restrict__ Bt,
                 void* __restrict__ C, const float* __restrict__ bias, int ldc) {
  __shared__ __hip_bfloat16 Asl[128 * 64];
  __shared__ __hip_bfloat16 Bsl[TN * 64];

  const int t = threadIdx.x;
  const int lane = t & 63;
  const int w = t >> 6;
  constexpr int MI = (TN == 128) ? 4 : 2;
  const int wrow = (TN == 128) ? (w >> 1) * 64 : w * 32;
  const int wcol = (TN == 128) ? (w & 1) * 64 : 0;
  const int m0 = blockIdx.y * 128;
  const int n0 = blockIdx.x * TN;

  f32x4 acc[MI][4];
#pragma unroll
  for (int i = 0; i < MI; i++)
#pragma unroll
    for (int j = 0; j < 4; j++) acc[i][j] = (f32x4){0.f, 0.f, 0.f, 0.f};

  const int srow = lane >> 3;
  const int sjc = (lane & 7) ^ srow;
  const int fm = lane & 15;
  const int g4 = lane >> 4;

  for (int k0 = 0; k0 < 1024; k0 += 64) {
#pragma unroll
    for (int i = 0; i < 4; i++) {
      int seg = i * 4 + w;
      int r = seg * 8 + srow;
      global_to_lds16(A + (size_t)(m0 + r) * 1024 + k0 + sjc * 8,
                      (void*)(Asl + seg * 512 + lane * 8));
    }
#pragma unroll
    for (int i = 0; i < TN / 32; i++) {
      int seg = i * 4 + w;
      int r = seg * 8 + srow;
      global_to_lds16(Bt + (size_t)(n0 + r) * 1024 + k0 + sjc * 8,
                      (void*)(Bsl + seg * 512 + lane * 8));
    }
    __syncthreads();
#pragma unroll
    for (int kb = 0; kb < 2; kb++) {
      bf16x8 af[MI], bfr[4];
#pragma unroll
      for (int mi = 0; mi < MI; mi++) {
        int row = wrow + mi * 16 + fm;
        af[mi] = *(const bf16x8*)(Asl + row * 64 + (((kb * 4 + g4) ^ (row & 7)) << 3));
      }
#pragma unroll
      for (int ni = 0; ni < 4; ni++) {
        int row = wcol + ni * 16 + fm;
        bfr[ni] = *(const bf16x8*)(Bsl + row * 64 + (((kb * 4 + g4) ^ (row & 7)) << 3));
      }
#pragma unroll
      for (int mi = 0; mi < MI; mi++)
#pragma unroll
        for (int ni = 0; ni < 4; ni++)
          acc[mi][ni] = __builtin_amdgcn_mfma_f32_16x16x32_bf16(af[mi], bfr[ni], acc[mi][ni], 0, 0, 0);
    }
    __syncthreads();
  }

#pragma unroll
  for (int mi = 0; mi < MI; mi++) {
    int mb = m0 + wrow + mi * 16 + g4 * 4;
#pragma unroll
    for (int ni = 0; ni < 4; ni++) {
      int n = n0 + wcol + ni * 16 + fm;
      float bv = OUT_BF16 ? 0.f : bias[n];
#pragma unroll
      for (int r = 0; r < 4; r++) {
        if (OUT_BF16)
          ((__hip_bfloat16*)C)[(size_t)(mb + r) * ldc + n] = __float2bfloat16(acc[mi][ni][r]);
        else
          ((float*)C)[(size_t)(mb + r) * ldc + n] = acc[mi][ni][r] + bv;
      }
    }
  }
}

// ---- causal flash attention: paired q-tiles, S^T in regs, PV via K=16 MFMA ----
// P conversion: truncation (bf16 = f32>>16) + v_perm pack — bias cancels in num/l ratio.
__global__ __launch_bounds__(256, 3)
void attn_kernel(const __hip_bfloat16* __restrict__ QKV,
                 const __hip_bfloat16* __restrict__ Vt,
                 __hip_bfloat16* __restrict__ ctx) {
  __shared__ __hip_bfloat16 Klds[2][64 * 64];    // [buf][kt][d], chunk j at slot j^(row&7)
  __shared__ __hip_bfloat16 Vlds[2][64 * 64];    // [buf][d][kt], same swizzle

  const int t = threadIdx.x;
  const int lane = t & 63;
  const int w = t >> 6;
  const int jb = blockIdx.x;               // 0..15
  const int qtab[2] = { jb, 31 - jb };
  const int bh = blockIdx.y;
  const int b = bh >> 4, h = bh & 15;
  const int fm = lane & 15;
  const int g4 = lane >> 4;
  const int fk = g4 * 8;
  const size_t rowb = (size_t)b * SEQ;
  const float c = 0.18033688011112042f;    // log2(e)/8

  const int krr = lane >> 3;
  const int kjc = (lane & 7) ^ krr;        // staging swizzle

  // Q fragments (MFMA B operands), prescaled by c
  bf16x8 qf[2][2];
#pragma unroll
  for (int hh = 0; hh < 2; hh++) {
    const __hip_bfloat16* qp = QKV + (rowb + qtab[hh] * 64 + w * 16 + fm) * 3072 + h * 64 + fk;
    bf16x8 r0 = *(const bf16x8*)qp;
    bf16x8 r1 = *(const bf16x8*)(qp + 32);
#pragma unroll
    for (int i = 0; i < 8; i++) {
      float f0 = __uint_as_float(((unsigned)(unsigned short)r0[i]) << 16) * c;
      float f1 = __uint_as_float(((unsigned)(unsigned short)r1[i]) << 16) * c;
      r0[i] = (short)f2bf_bits(f0);
      r1[i] = (short)f2bf_bits(f1);
    }
    qf[hh][0] = r0; qf[hh][1] = r1;
  }

  bf16x4 ones4;
#pragma unroll
  for (int i = 0; i < 4; i++) ones4[i] = (short)0x3F80;

  f32x4 acc[2][4];
  f32x4 lacc[2];
#pragma unroll
  for (int hh = 0; hh < 2; hh++) {
    lacc[hh] = (f32x4){0.f, 0.f, 0.f, 0.f};
#pragma unroll
    for (int d = 0; d < 4; d++) acc[hh][d] = (f32x4){0.f, 0.f, 0.f, 0.f};
  }

  auto stage = [&](int kts, int bufi) {
    const int kt0 = kts * 64;
#pragma unroll
    for (int i = 0; i < 2; i++) {
      int seg = w + i * 4;
      int r = seg * 8 + krr;
      global_to_lds16(QKV + (rowb + kt0 + r) * 3072 + 1024 + h * 64 + kjc * 8,
                      (void*)(&Klds[bufi][0] + seg * 512 + lane * 8));
      global_to_lds16(Vt + ((size_t)bh * 64 + r) * 2048 + kt0 + kjc * 8,
                      (void*)(&Vlds[bufi][0] + seg * 512 + lane * 8));
    }
  };

  const int lastt = qtab[1];
  stage(0, 0);
  for (int kts = 0; kts <= lastt; ++kts) {
    __syncthreads();
    if (kts < lastt) stage(kts + 1, (kts + 1) & 1);
    const __hip_bfloat16* Kb = &Klds[kts & 1][0];
    const __hip_bfloat16* Vb = &Vlds[kts & 1][0];
    const bool act0 = (kts <= qtab[0]);

    // V B-fragments for K=16 MFMA, hoisted so ds_read latency hides under QK MFMAs
    bf16x4 vf[4][4];   // [dd][ns]
#pragma unroll
    for (int dd = 0; dd < 4; dd++)
#pragma unroll
      for (int ns = 0; ns < 4; ns++)
        vf[dd][ns] = *(const bf16x4*)(Vb + (dd * 16 + fm) * 64 +
                                      (((2 * ns + (g4 >> 1)) ^ (fm & 7)) << 3) + (g4 & 1) * 4);

    // S^T = K Q^T for both halves (kf loads shared)
    f32x4 st1[4], st0[4];
#pragma unroll
    for (int ns = 0; ns < 4; ns++) {
      st1[ns] = (f32x4){0.f, 0.f, 0.f, 0.f};
      st0[ns] = (f32x4){0.f, 0.f, 0.f, 0.f};
    }
#pragma unroll
    for (int kk = 0; kk < 2; kk++) {
      bf16x8 kf[4];
#pragma unroll
      for (int ns = 0; ns < 4; ns++)
        kf[ns] = *(const bf16x8*)(Kb + (ns * 16 + fm) * 64 + (((kk * 4 + g4) ^ (fm & 7)) << 3));
#pragma unroll
      for (int ns = 0; ns < 4; ns++)
        st1[ns] = __builtin_amdgcn_mfma_f32_16x16x32_bf16(kf[ns], qf[1][kk], st1[ns], 0, 0, 0);
      if (act0)
#pragma unroll
        for (int ns = 0; ns < 4; ns++)
          st0[ns] = __builtin_amdgcn_mfma_f32_16x16x32_bf16(kf[ns], qf[0][kk], st0[ns], 0, 0, 0);
    }

    // per half: exp2 -> truncate-pack (v_perm) -> PV + rowsum MFMAs, all in registers
    auto half = [&](const f32x4 (&st)[4], int hh) {
      const bool diag = (kts == qtab[hh]);
#pragma unroll
      for (int ns = 0; ns < 4; ns++) {
        float e[4];
#pragma unroll
        for (int r = 0; r < 4; r++) {
          float p = __builtin_amdgcn_exp2f(st[ns][r]);
          if (diag) {
            int ktl = ns * 16 + g4 * 4 + r;
            p = (ktl > w * 16 + fm) ? 0.f : p;
          }
          e[r] = p;
        }
        // pack 4 f32 -> 4 bf16 by truncation: one v_perm per pair
        unsigned lo = __builtin_amdgcn_perm(__builtin_bit_cast(unsigned, e[1]),
                                            __builtin_bit_cast(unsigned, e[0]), 0x07060302u);
        unsigned hi = __builtin_amdgcn_perm(__builtin_bit_cast(unsigned, e[3]),
                                            __builtin_bit_cast(unsigned, e[2]), 0x07060302u);
        uint2 pp; pp.x = lo; pp.y = hi;
        bf16x4 pf = __builtin_bit_cast(bf16x4, pp);
        lacc[hh] = __builtin_amdgcn_mfma_f32_16x16x16bf16_1k(pf, ones4, lacc[hh], 0, 0, 0);
#pragma unroll
        for (int dd = 0; dd < 4; dd++)
          acc[hh][dd] = __builtin_amdgcn_mfma_f32_16x16x16bf16_1k(pf, vf[dd][ns], acc[hh][dd], 0, 0, 0);
      }
    };
    half(st1, 1);
    if (act0) half(st0, 0);
  }

  // epilogue: ctx = acc * rcp(l)
#pragma unroll
  for (int hh = 0; hh < 2; hh++) {
    float rl[4];
#pragma unroll
    for (int r = 0; r < 4; r++) rl[r] = __builtin_amdgcn_rcpf(lacc[hh][r]);
#pragma unroll
    for (int dd = 0; dd < 4; dd++)
#pragma unroll
      for (int r = 0; r < 4; r++) {
        int q = qtab[hh] * 64 + w * 16 + g4 * 4 + r;
        ctx[(rowb + q) * 1024 + h * 64 + dd * 16 + fm] =
            __float2bfloat16(acc[hh][dd][r] * rl[r]);
      }
  }
}

// ---------------- launch ----------------
extern "C" void kernel_launch(void* const* d_in, const int* in_sizes, int n_in,
                              void* d_out, int out_size, void* d_ws, size_t ws_size,
                              hipStream_t stream) {
  const float* x  = (const float*)d_in[0];
  const float* Wq = (const float*)d_in[1];
  const float* Wk = (const float*)d_in[2];
  const float* Wv = (const float*)d_in[3];
  const float* Wo = (const float*)d_in[4];
  const float* bo = (const float*)d_in[5];
  float* out = (float*)d_out;

  char* ws = (char*)d_ws;
  __hip_bfloat16* xb     = (__hip_bfloat16*)(ws);                      // 8 MiB (reused as Vt)
  __hip_bfloat16* Wqkv_t = (__hip_bfloat16*)(ws + (8ull  << 20));      // 6 MiB
  __hip_bfloat16* Wo_t   = (__hip_bfloat16*)(ws + (14ull << 20));      // 2 MiB
  __hip_bfloat16* QKV    = (__hip_bfloat16*)(ws + (16ull << 20));      // 24 MiB
  __hip_bfloat16* ctxb   = (__hip_bfloat16*)(ws + (40ull << 20));      // 8 MiB
  __hip_bfloat16* Vt     = xb;  // xb dead after QKV GEMM; reuse

  cvt_x<<<dim3(MROWS * DMODEL / (256 * 4)), dim3(256), 0, stream>>>(x, xb);
  trans_w<<<dim3(32, 32, 4), dim3(256), 0, stream>>>(Wq, Wk, Wv, Wo, Wqkv_t, Wo_t);
  gemm_kernel<128, true, 3><<<dim3(24, 32), dim3(256), 0, stream>>>(xb, Wqkv_t, (void*)QKV, nullptr, 3072);
  trans_v<<<dim3(32, 32), dim3(256), 0, stream>>>(QKV, Vt);
  attn_kernel<<<dim3(16, 32), dim3(256), 0, stream>>>(QKV, Vt, ctxb);
  gemm_kernel<64, false, 2><<<dim3(16, 32), dim3(256), 0, stream>>>(ctxb, Wo_t, (void*)out, bo, 1024);
}

// Round 9
// 186.193 us; speedup vs baseline: 1.0207x; 1.0207x over previous
//
#include <hip/hip_runtime.h>
#include <hip/hip_bf16.h>
#include <stdint.h>

#define SEQ    2048
#define BATCH  2
#define DMODEL 1024
#define NHEADS 16
#define HDIM   64
#define MROWS  (BATCH*SEQ)   // 4096

typedef __attribute__((ext_vector_type(8))) short bf16x8;
typedef __attribute__((ext_vector_type(4))) short bf16x4;
typedef __attribute__((ext_vector_type(4))) float f32x4;

__device__ inline void global_to_lds16(const void* g, void* l) {
  __builtin_amdgcn_global_load_lds(
      (const __attribute__((address_space(1))) uint32_t*)g,
      (__attribute__((address_space(3))) uint32_t*)l, 16, 0, 0);
}

__device__ inline unsigned short f2bf_bits(float f) {
  __hip_bfloat16 h = __float2bfloat16(f);
  return *(unsigned short*)&h;
}

// ---------------- x -> bf16 ----------------
__global__ void cvt_x(const float* __restrict__ x, __hip_bfloat16* __restrict__ xb) {
  int i = (blockIdx.x * 256 + threadIdx.x) * 4;
  float4 v = *(const float4*)(x + i);
  ushort4 o;
  o.x = f2bf_bits(v.x); o.y = f2bf_bits(v.y);
  o.z = f2bf_bits(v.z); o.w = f2bf_bits(v.w);
  *(ushort4*)(xb + i) = o;
}

// ------- W [k][n] f32 -> Wt [n][k] bf16 (tiled transpose) -------
__global__ void trans_w(const float* __restrict__ Wq, const float* __restrict__ Wk,
                        const float* __restrict__ Wv, const float* __restrict__ Wo,
                        __hip_bfloat16* __restrict__ Wqkv_t, __hip_bfloat16* __restrict__ Wo_t) {
  __shared__ float tile[32][33];
  int z = blockIdx.z;
  const float* W = (z == 0) ? Wq : (z == 1) ? Wk : (z == 2) ? Wv : Wo;
  __hip_bfloat16* dst = (z < 3) ? (Wqkv_t + (size_t)z * 1024 * 1024) : Wo_t;
  int k0 = blockIdx.x * 32, n0 = blockIdx.y * 32;
  int tx = threadIdx.x & 31, ty = threadIdx.x >> 5;
#pragma unroll
  for (int r = 0; r < 4; r++)
    tile[ty + r * 8][tx] = W[(size_t)(k0 + ty + r * 8) * 1024 + n0 + tx];
  __syncthreads();
#pragma unroll
  for (int r = 0; r < 4; r++)
    dst[(size_t)(n0 + ty + r * 8) * 1024 + k0 + tx] = __float2bfloat16(tile[tx][ty + r * 8]);
}

// ------- V slice of QKV -> Vt[bh][d=64][s=2048] bf16 -------
__global__ void trans_v(const __hip_bfloat16* __restrict__ QKV, __hip_bfloat16* __restrict__ Vt) {
  __shared__ __hip_bfloat16 tile[64][72];
  int bh = blockIdx.y;
  int b = bh >> 4, h = bh & 15;
  int s0 = blockIdx.x * 64;
  int t = threadIdx.x;
  int r = t >> 2, cg = (t & 3) * 16;
  const __hip_bfloat16* src = QKV + ((size_t)(b * SEQ + s0 + r)) * 3072 + 2048 + h * 64 + cg;
  *(uint4*)&tile[r][cg]     = *(const uint4*)src;
  *(uint4*)&tile[r][cg + 8] = *(const uint4*)(src + 8);
  __syncthreads();
  unsigned short tmp[16];
#pragma unroll
  for (int i = 0; i < 16; i++) tmp[i] = *(const unsigned short*)&tile[cg + i][r];
  __hip_bfloat16* dst = Vt + ((size_t)bh * 64 + r) * 2048 + s0 + cg;
  *(uint4*)dst       = *(const uint4*)&tmp[0];
  *(uint4*)(dst + 8) = *(const uint4*)&tmp[8];
}

// ------ GEMM: C[M][ldc] = A[M][1024]*Wt[N][1024]^T (+bias), BK=64, swizzled LDS ------
template <int TN, bool OUT_BF16, int MINW>
__global__ __launch_bounds__(256, MINW)
void gemm_kernel(const __hip_bfloat16* __restrict__ A, const __hip_bfloat16* __restrict__ Bt,
                 void* __restrict__ C, const float* __restrict__ bias, int ldc) {
  __shared__ __hip_bfloat16 Asl[128 * 64];
  __shared__ __hip_bfloat16 Bsl[TN * 64];

  const int t = threadIdx.x;
  const int lane = t & 63;
  const int w = t >> 6;
  constexpr int MI = (TN == 128) ? 4 : 2;
  const int wrow = (TN == 128) ? (w >> 1) * 64 : w * 32;
  const int wcol = (TN == 128) ? (w & 1) * 64 : 0;
  const int m0 = blockIdx.y * 128;
  const int n0 = blockIdx.x * TN;

  f32x4 acc[MI][4];
#pragma unroll
  for (int i = 0; i < MI; i++)
#pragma unroll
    for (int j = 0; j < 4; j++) acc[i][j] = (f32x4){0.f, 0.f, 0.f, 0.f};

  const int srow = lane >> 3;
  const int sjc = (lane & 7) ^ srow;
  const int fm = lane & 15;
  const int g4 = lane >> 4;

  for (int k0 = 0; k0 < 1024; k0 += 64) {
#pragma unroll
    for (int i = 0; i < 4; i++) {
      int seg = i * 4 + w;
      int r = seg * 8 + srow;
      global_to_lds16(A + (size_t)(m0 + r) * 1024 + k0 + sjc * 8,
                      (void*)(Asl + seg * 512 + lane * 8));
    }
#pragma unroll
    for (int i = 0; i < TN / 32; i++) {
      int seg = i * 4 + w;
      int r = seg * 8 + srow;
      global_to_lds16(Bt + (size_t)(n0 + r) * 1024 + k0 + sjc * 8,
                      (void*)(Bsl + seg * 512 + lane * 8));
    }
    __syncthreads();
#pragma unroll
    for (int kb = 0; kb < 2; kb++) {
      bf16x8 af[MI], bfr[4];
#pragma unroll
      for (int mi = 0; mi < MI; mi++) {
        int row = wrow + mi * 16 + fm;
        af[mi] = *(const bf16x8*)(Asl + row * 64 + (((kb * 4 + g4) ^ (row & 7)) << 3));
      }
#pragma unroll
      for (int ni = 0; ni < 4; ni++) {
        int row = wcol + ni * 16 + fm;
        bfr[ni] = *(const bf16x8*)(Bsl + row * 64 + (((kb * 4 + g4) ^ (row & 7)) << 3));
      }
#pragma unroll
      for (int mi = 0; mi < MI; mi++)
#pragma unroll
        for (int ni = 0; ni < 4; ni++)
          acc[mi][ni] = __builtin_amdgcn_mfma_f32_16x16x32_bf16(af[mi], bfr[ni], acc[mi][ni], 0, 0, 0);
    }
    __syncthreads();
  }

#pragma unroll
  for (int mi = 0; mi < MI; mi++) {
    int mb = m0 + wrow + mi * 16 + g4 * 4;
#pragma unroll
    for (int ni = 0; ni < 4; ni++) {
      int n = n0 + wcol + ni * 16 + fm;
      float bv = OUT_BF16 ? 0.f : bias[n];
#pragma unroll
      for (int r = 0; r < 4; r++) {
        if (OUT_BF16)
          ((__hip_bfloat16*)C)[(size_t)(mb + r) * ldc + n] = __float2bfloat16(acc[mi][ni][r]);
        else
          ((float*)C)[(size_t)(mb + r) * ldc + n] = acc[mi][ni][r] + bv;
      }
    }
  }
}

// ---- causal flash attention: 512-thread blocks, 2 q-tile pairs share staged K/V ----
// Waves 0-3: q-tiles (2j, 31-2j); waves 4-7: (2j+1, 30-2j). One K/V staging serves
// both groups -> per-CU staging bytes halved (the R5-R7 plateau was L2-BW-bound).
// S^T in regs (q=fm, kt=ns*16+g4*4+r = K=16 A-fragment); PV direct from registers.
__global__ __launch_bounds__(512, 2)
void attn_kernel(const __hip_bfloat16* __restrict__ QKV,
                 const __hip_bfloat16* __restrict__ Vt,
                 __hip_bfloat16* __restrict__ ctx) {
  __shared__ __hip_bfloat16 Klds[2][64 * 64];    // [buf][kt][d], chunk j at slot j^(row&7)
  __shared__ __hip_bfloat16 Vlds[2][64 * 64];    // [buf][d][kt], same swizzle

  const int t = threadIdx.x;
  const int lane = t & 63;
  const int w = t >> 6;                    // 0..7
  const int grp = w >> 2;                  // 0,1: which q-tile pair
  const int wl = w & 3;                    // 16-row strip within 64-row tile
  const int j = blockIdx.x;                // 0..7
  const int qtab[2] = { grp == 0 ? 2 * j : 2 * j + 1,
                        grp == 0 ? 31 - 2 * j : 30 - 2 * j };
  const int bh = blockIdx.y;
  const int b = bh >> 4, h = bh & 15;
  const int fm = lane & 15;
  const int g4 = lane >> 4;
  const int fk = g4 * 8;
  const size_t rowb = (size_t)b * SEQ;
  const float c = 0.18033688011112042f;    // log2(e)/8

  const int krr = lane >> 3;
  const int kjc = (lane & 7) ^ krr;        // staging swizzle

  // Q fragments (MFMA B operands), prescaled by c
  bf16x8 qf[2][2];
#pragma unroll
  for (int hh = 0; hh < 2; hh++) {
    const __hip_bfloat16* qp = QKV + (rowb + qtab[hh] * 64 + wl * 16 + fm) * 3072 + h * 64 + fk;
    bf16x8 r0 = *(const bf16x8*)qp;
    bf16x8 r1 = *(const bf16x8*)(qp + 32);
#pragma unroll
    for (int i = 0; i < 8; i++) {
      float f0 = __uint_as_float(((unsigned)(unsigned short)r0[i]) << 16) * c;
      float f1 = __uint_as_float(((unsigned)(unsigned short)r1[i]) << 16) * c;
      r0[i] = (short)f2bf_bits(f0);
      r1[i] = (short)f2bf_bits(f1);
    }
    qf[hh][0] = r0; qf[hh][1] = r1;
  }

  bf16x4 ones4;
#pragma unroll
  for (int i = 0; i < 4; i++) ones4[i] = (short)0x3F80;

  f32x4 acc[2][4];
  f32x4 lacc[2];
#pragma unroll
  for (int hh = 0; hh < 2; hh++) {
    lacc[hh] = (f32x4){0.f, 0.f, 0.f, 0.f};
#pragma unroll
    for (int d = 0; d < 4; d++) acc[hh][d] = (f32x4){0.f, 0.f, 0.f, 0.f};
  }

  // 512 threads stage the whole 8KB K + 8KB V tile in one shot (seg = w)
  auto stage = [&](int kts, int bufi) {
    const int kt0 = kts * 64;
    int r = w * 8 + krr;                   // 0..63
    global_to_lds16(QKV + (rowb + kt0 + r) * 3072 + 1024 + h * 64 + kjc * 8,
                    (void*)(&Klds[bufi][0] + w * 512 + lane * 8));
    global_to_lds16(Vt + ((size_t)bh * 64 + r) * 2048 + kt0 + kjc * 8,
                    (void*)(&Vlds[bufi][0] + w * 512 + lane * 8));
  };

  const int lastt = 31 - 2 * j;            // block-uniform loop bound
  stage(0, 0);
  for (int kts = 0; kts <= lastt; ++kts) {
    __syncthreads();
    if (kts < lastt) stage(kts + 1, (kts + 1) & 1);
    const __hip_bfloat16* Kb = &Klds[kts & 1][0];
    const __hip_bfloat16* Vb = &Vlds[kts & 1][0];
    const bool act0 = (kts <= qtab[0]);
    const bool act1 = (kts <= qtab[1]);    // false only for grp1 on the last tile

    // S^T = K Q^T (kf loads shared across both halves; issued before vf — consumption order)
    f32x4 st1[4], st0[4];
#pragma unroll
    for (int ns = 0; ns < 4; ns++) {
      st1[ns] = (f32x4){0.f, 0.f, 0.f, 0.f};
      st0[ns] = (f32x4){0.f, 0.f, 0.f, 0.f};
    }
#pragma unroll
    for (int kk = 0; kk < 2; kk++) {
      bf16x8 kf[4];
#pragma unroll
      for (int ns = 0; ns < 4; ns++)
        kf[ns] = *(const bf16x8*)(Kb + (ns * 16 + fm) * 64 + (((kk * 4 + g4) ^ (fm & 7)) << 3));
      if (act1)
#pragma unroll
        for (int ns = 0; ns < 4; ns++)
          st1[ns] = __builtin_amdgcn_mfma_f32_16x16x32_bf16(kf[ns], qf[1][kk], st1[ns], 0, 0, 0);
      if (act0)
#pragma unroll
        for (int ns = 0; ns < 4; ns++)
          st0[ns] = __builtin_amdgcn_mfma_f32_16x16x32_bf16(kf[ns], qf[0][kk], st0[ns], 0, 0, 0);
    }

    // V B-fragments for K=16 MFMA (after QK so kf reads retire first), shared by halves
    bf16x4 vf[4][4];   // [dd][ns]
#pragma unroll
    for (int dd = 0; dd < 4; dd++)
#pragma unroll
      for (int ns = 0; ns < 4; ns++)
        vf[dd][ns] = *(const bf16x4*)(Vb + (dd * 16 + fm) * 64 +
                                      (((2 * ns + (g4 >> 1)) ^ (fm & 7)) << 3) + (g4 & 1) * 4);

    // per half: exp2 -> truncate-pack (v_perm) -> PV + rowsum MFMAs, all in registers
    auto half = [&](const f32x4 (&st)[4], int hh) {
      const bool diag = (kts == qtab[hh]);
#pragma unroll
      for (int ns = 0; ns < 4; ns++) {
        float e[4];
#pragma unroll
        for (int r = 0; r < 4; r++) {
          float p = __builtin_amdgcn_exp2f(st[ns][r]);
          if (diag) {
            int ktl = ns * 16 + g4 * 4 + r;
            p = (ktl > wl * 16 + fm) ? 0.f : p;
          }
          e[r] = p;
        }
        unsigned lo = __builtin_amdgcn_perm(__builtin_bit_cast(unsigned, e[1]),
                                            __builtin_bit_cast(unsigned, e[0]), 0x07060302u);
        unsigned hi = __builtin_amdgcn_perm(__builtin_bit_cast(unsigned, e[3]),
                                            __builtin_bit_cast(unsigned, e[2]), 0x07060302u);
        uint2 pp; pp.x = lo; pp.y = hi;
        bf16x4 pf = __builtin_bit_cast(bf16x4, pp);
        lacc[hh] = __builtin_amdgcn_mfma_f32_16x16x16bf16_1k(pf, ones4, lacc[hh], 0, 0, 0);
#pragma unroll
        for (int dd = 0; dd < 4; dd++)
          acc[hh][dd] = __builtin_amdgcn_mfma_f32_16x16x16bf16_1k(pf, vf[dd][ns], acc[hh][dd], 0, 0, 0);
      }
    };
    if (act1) half(st1, 1);
    if (act0) half(st0, 0);
  }

  // epilogue: ctx = acc * rcp(l)
#pragma unroll
  for (int hh = 0; hh < 2; hh++) {
    float rl[4];
#pragma unroll
    for (int r = 0; r < 4; r++) rl[r] = __builtin_amdgcn_rcpf(lacc[hh][r]);
#pragma unroll
    for (int dd = 0; dd < 4; dd++)
#pragma unroll
      for (int r = 0; r < 4; r++) {
        int q = qtab[hh] * 64 + wl * 16 + g4 * 4 + r;
        ctx[(rowb + q) * 1024 + h * 64 + dd * 16 + fm] =
            __float2bfloat16(acc[hh][dd][r] * rl[r]);
      }
  }
}

// ---------------- launch ----------------
extern "C" void kernel_launch(void* const* d_in, const int* in_sizes, int n_in,
                              void* d_out, int out_size, void* d_ws, size_t ws_size,
                              hipStream_t stream) {
  const float* x  = (const float*)d_in[0];
  const float* Wq = (const float*)d_in[1];
  const float* Wk = (const float*)d_in[2];
  const float* Wv = (const float*)d_in[3];
  const float* Wo = (const float*)d_in[4];
  const float* bo = (const float*)d_in[5];
  float* out = (float*)d_out;

  char* ws = (char*)d_ws;
  __hip_bfloat16* xb     = (__hip_bfloat16*)(ws);                      // 8 MiB (reused as Vt)
  __hip_bfloat16* Wqkv_t = (__hip_bfloat16*)(ws + (8ull  << 20));      // 6 MiB
  __hip_bfloat16* Wo_t   = (__hip_bfloat16*)(ws + (14ull << 20));      // 2 MiB
  __hip_bfloat16* QKV    = (__hip_bfloat16*)(ws + (16ull << 20));      // 24 MiB
  __hip_bfloat16* ctxb   = (__hip_bfloat16*)(ws + (40ull << 20));      // 8 MiB
  __hip_bfloat16* Vt     = xb;  // xb dead after QKV GEMM; reuse

  cvt_x<<<dim3(MROWS * DMODEL / (256 * 4)), dim3(256), 0, stream>>>(x, xb);
  trans_w<<<dim3(32, 32, 4), dim3(256), 0, stream>>>(Wq, Wk, Wv, Wo, Wqkv_t, Wo_t);
  gemm_kernel<128, true, 3><<<dim3(24, 32), dim3(256), 0, stream>>>(xb, Wqkv_t, (void*)QKV, nullptr, 3072);
  trans_v<<<dim3(32, 32), dim3(256), 0, stream>>>(QKV, Vt);
  attn_kernel<<<dim3(8, 32), dim3(512), 0, stream>>>(QKV, Vt, ctxb);
  gemm_kernel<64, false, 2><<<dim3(16, 32), dim3(256), 0, stream>>>(ctxb, Wo_t, (void*)out, bo, 1024);
}

// Round 10
// 175.580 us; speedup vs baseline: 1.0824x; 1.0604x over previous
//
#include <hip/hip_runtime.h>
#include <hip/hip_bf16.h>
#include <stdint.h>

#define SEQ    2048
#define BATCH  2
#define DMODEL 1024
#define NHEADS 16
#define HDIM   64
#define MROWS  (BATCH*SEQ)   // 4096

typedef __attribute__((ext_vector_type(8))) short bf16x8;
typedef __attribute__((ext_vector_type(4))) short bf16x4;
typedef __attribute__((ext_vector_type(4))) float f32x4;

__device__ inline void global_to_lds16(const void* g, void* l) {
  __builtin_amdgcn_global_load_lds(
      (const __attribute__((address_space(1))) uint32_t*)g,
      (__attribute__((address_space(3))) uint32_t*)l, 16, 0, 0);
}

__device__ inline unsigned short f2bf_bits(float f) {
  __hip_bfloat16 h = __float2bfloat16(f);
  return *(unsigned short*)&h;
}

// ---------------- x -> bf16 ----------------
__global__ void cvt_x(const float* __restrict__ x, __hip_bfloat16* __restrict__ xb) {
  int i = (blockIdx.x * 256 + threadIdx.x) * 4;
  float4 v = *(const float4*)(x + i);
  ushort4 o;
  o.x = f2bf_bits(v.x); o.y = f2bf_bits(v.y);
  o.z = f2bf_bits(v.z); o.w = f2bf_bits(v.w);
  *(ushort4*)(xb + i) = o;
}

// ------- W [k][n] f32 -> Wt [n][k] bf16 (tiled transpose) -------
__global__ void trans_w(const float* __restrict__ Wq, const float* __restrict__ Wk,
                        const float* __restrict__ Wv, const float* __restrict__ Wo,
                        __hip_bfloat16* __restrict__ Wqkv_t, __hip_bfloat16* __restrict__ Wo_t) {
  __shared__ float tile[32][33];
  int z = blockIdx.z;
  const float* W = (z == 0) ? Wq : (z == 1) ? Wk : (z == 2) ? Wv : Wo;
  __hip_bfloat16* dst = (z < 3) ? (Wqkv_t + (size_t)z * 1024 * 1024) : Wo_t;
  int k0 = blockIdx.x * 32, n0 = blockIdx.y * 32;
  int tx = threadIdx.x & 31, ty = threadIdx.x >> 5;
#pragma unroll
  for (int r = 0; r < 4; r++)
    tile[ty + r * 8][tx] = W[(size_t)(k0 + ty + r * 8) * 1024 + n0 + tx];
  __syncthreads();
#pragma unroll
  for (int r = 0; r < 4; r++)
    dst[(size_t)(n0 + ty + r * 8) * 1024 + k0 + tx] = __float2bfloat16(tile[tx][ty + r * 8]);
}

// ------- V slice of QKV -> Vt[bh][d=64][s=2048] bf16 -------
__global__ void trans_v(const __hip_bfloat16* __restrict__ QKV, __hip_bfloat16* __restrict__ Vt) {
  __shared__ __hip_bfloat16 tile[64][72];
  int bh = blockIdx.y;
  int b = bh >> 4, h = bh & 15;
  int s0 = blockIdx.x * 64;
  int t = threadIdx.x;
  int r = t >> 2, cg = (t & 3) * 16;
  const __hip_bfloat16* src = QKV + ((size_t)(b * SEQ + s0 + r)) * 3072 + 2048 + h * 64 + cg;
  *(uint4*)&tile[r][cg]     = *(const uint4*)src;
  *(uint4*)&tile[r][cg + 8] = *(const uint4*)(src + 8);
  __syncthreads();
  unsigned short tmp[16];
#pragma unroll
  for (int i = 0; i < 16; i++) tmp[i] = *(const unsigned short*)&tile[cg + i][r];
  __hip_bfloat16* dst = Vt + ((size_t)bh * 64 + r) * 2048 + s0 + cg;
  *(uint4*)dst       = *(const uint4*)&tmp[0];
  *(uint4*)(dst + 8) = *(const uint4*)&tmp[8];
}

// ------ GEMM: C[M][ldc] = A[M][1024]*Wt[N][1024]^T (+bias), BK=64, swizzled LDS ------
template <int TN, bool OUT_BF16, int MINW>
__global__ __launch_bounds__(256, MINW)
void gemm_kernel(const __hip_bfloat16* __restrict__ A, const __hip_bfloat16* __restrict__ Bt,
                 void* __restrict__ C, const float* __restrict__ bias, int ldc) {
  __shared__ __hip_bfloat16 Asl[128 * 64];
  __shared__ __hip_bfloat16 Bsl[TN * 64];

  const int t = threadIdx.x;
  const int lane = t & 63;
  const int w = t >> 6;
  constexpr int MI = (TN == 128) ? 4 : 2;
  const int wrow = (TN == 128) ? (w >> 1) * 64 : w * 32;
  const int wcol = (TN == 128) ? (w & 1) * 64 : 0;
  const int m0 = blockIdx.y * 128;
  const int n0 = blockIdx.x * TN;

  f32x4 acc[MI][4];
#pragma unroll
  for (int i = 0; i < MI; i++)
#pragma unroll
    for (int j = 0; j < 4; j++) acc[i][j] = (f32x4){0.f, 0.f, 0.f, 0.f};

  const int srow = lane >> 3;
  const int sjc = (lane & 7) ^ srow;
  const int fm = lane & 15;
  const int g4 = lane >> 4;

  for (int k0 = 0; k0 < 1024; k0 += 64) {
#pragma unroll
    for (int i = 0; i < 4; i++) {
      int seg = i * 4 + w;
      int r = seg * 8 + srow;
      global_to_lds16(A + (size_t)(m0 + r) * 1024 + k0 + sjc * 8,
                      (void*)(Asl + seg * 512 + lane * 8));
    }
#pragma unroll
    for (int i = 0; i < TN / 32; i++) {
      int seg = i * 4 + w;
      int r = seg * 8 + srow;
      global_to_lds16(Bt + (size_t)(n0 + r) * 1024 + k0 + sjc * 8,
                      (void*)(Bsl + seg * 512 + lane * 8));
    }
    __syncthreads();
#pragma unroll
    for (int kb = 0; kb < 2; kb++) {
      bf16x8 af[MI], bfr[4];
#pragma unroll
      for (int mi = 0; mi < MI; mi++) {
        int row = wrow + mi * 16 + fm;
        af[mi] = *(const bf16x8*)(Asl + row * 64 + (((kb * 4 + g4) ^ (row & 7)) << 3));
      }
#pragma unroll
      for (int ni = 0; ni < 4; ni++) {
        int row = wcol + ni * 16 + fm;
        bfr[ni] = *(const bf16x8*)(Bsl + row * 64 + (((kb * 4 + g4) ^ (row & 7)) << 3));
      }
#pragma unroll
      for (int mi = 0; mi < MI; mi++)
#pragma unroll
        for (int ni = 0; ni < 4; ni++)
          acc[mi][ni] = __builtin_amdgcn_mfma_f32_16x16x32_bf16(af[mi], bfr[ni], acc[mi][ni], 0, 0, 0);
    }
    __syncthreads();
  }

#pragma unroll
  for (int mi = 0; mi < MI; mi++) {
    int mb = m0 + wrow + mi * 16 + g4 * 4;
#pragma unroll
    for (int ni = 0; ni < 4; ni++) {
      int n = n0 + wcol + ni * 16 + fm;
      float bv = OUT_BF16 ? 0.f : bias[n];
#pragma unroll
      for (int r = 0; r < 4; r++) {
        if (OUT_BF16)
          ((__hip_bfloat16*)C)[(size_t)(mb + r) * ldc + n] = __float2bfloat16(acc[mi][ni][r]);
        else
          ((float*)C)[(size_t)(mb + r) * ldc + n] = acc[mi][ni][r] + bv;
      }
    }
  }
}

// ---- causal flash attention: paired q-tiles, 128-kt dbuf phases, S^T+reg-PV core ----
// 128-kt phases double the prefetch window (covers ~900cyc HBM latency) and halve
// barriers. jb swizzle makes co-resident blocks (x,y),(x,y+16) complementary so
// per-CU staging is uniform (49 tile-units).
__global__ __launch_bounds__(256, 2)
void attn_kernel(const __hip_bfloat16* __restrict__ QKV,
                 const __hip_bfloat16* __restrict__ Vt,
                 __hip_bfloat16* __restrict__ ctx) {
  __shared__ __hip_bfloat16 Klds[2][128 * 64];   // [buf][kt][d], chunk j at slot j^(row&7)
  __shared__ __hip_bfloat16 Vlds[2][64 * 128];   // [buf][d][kt], chunk j at slot j^(d&7)

  const int t = threadIdx.x;
  const int lane = t & 63;
  const int w = t >> 6;                    // 0..3
  const int bh = blockIdx.y;
  const int jb = (int)blockIdx.x ^ ((bh & 16) ? 15 : 0);   // CU-balance swizzle
  const int qtab[2] = { jb, 31 - jb };
  const int b = bh >> 4, h = bh & 15;
  const int fm = lane & 15;
  const int g4 = lane >> 4;
  const int fk = g4 * 8;
  const size_t rowb = (size_t)b * SEQ;
  const float c = 0.18033688011112042f;    // log2(e)/8

  const int krr = lane >> 3;               // 0..7
  const int kjc = (lane & 7) ^ krr;        // K staging swizzle
  const int vrr = lane >> 4;               // 0..3

  // Q fragments (MFMA B operands), prescaled by c
  bf16x8 qf[2][2];
#pragma unroll
  for (int hh = 0; hh < 2; hh++) {
    const __hip_bfloat16* qp = QKV + (rowb + qtab[hh] * 64 + w * 16 + fm) * 3072 + h * 64 + fk;
    bf16x8 r0 = *(const bf16x8*)qp;
    bf16x8 r1 = *(const bf16x8*)(qp + 32);
#pragma unroll
    for (int i = 0; i < 8; i++) {
      float f0 = __uint_as_float(((unsigned)(unsigned short)r0[i]) << 16) * c;
      float f1 = __uint_as_float(((unsigned)(unsigned short)r1[i]) << 16) * c;
      r0[i] = (short)f2bf_bits(f0);
      r1[i] = (short)f2bf_bits(f1);
    }
    qf[hh][0] = r0; qf[hh][1] = r1;
  }

  bf16x4 ones4;
#pragma unroll
  for (int i = 0; i < 4; i++) ones4[i] = (short)0x3F80;

  f32x4 acc[2][4];
  f32x4 lacc[2];
#pragma unroll
  for (int hh = 0; hh < 2; hh++) {
    lacc[hh] = (f32x4){0.f, 0.f, 0.f, 0.f};
#pragma unroll
    for (int d = 0; d < 4; d++) acc[hh][d] = (f32x4){0.f, 0.f, 0.f, 0.f};
  }

  // stage one 128-kt phase: K 16KB (16 segs of 8 rows) + V 16KB (16 segs of 4 d-rows)
  auto stage = [&](int pt, int bufi) {
    const int kt0 = pt * 128;
#pragma unroll
    for (int i = 0; i < 4; i++) {
      int seg = i * 4 + w;                 // 0..15
      int kr = seg * 8 + krr;              // K row 0..127
      global_to_lds16(QKV + (rowb + kt0 + kr) * 3072 + 1024 + h * 64 + kjc * 8,
                      (void*)(&Klds[bufi][0] + seg * 512 + lane * 8));
      int vd = seg * 4 + vrr;              // Vt d-row 0..63
      int vjc = (lane & 15) ^ ((seg & 1) * 4 + vrr);   // slot lane&15 holds chunk slot^(d&7)
      global_to_lds16(Vt + ((size_t)bh * 64 + vd) * 2048 + kt0 + vjc * 8,
                      (void*)(&Vlds[bufi][0] + seg * 512 + lane * 8));
    }
  };

  const int lastt = qtab[1];               // 16..31
  const int lastp = lastt >> 1;            // last phase index
  stage(0, 0);
  for (int pt = 0; pt <= lastp; ++pt) {
    __syncthreads();                       // drains phase-pt loads
    if (pt < lastp) stage(pt + 1, (pt + 1) & 1);   // prefetch: full 2-sub-tile window
    const __hip_bfloat16* Kb = &Klds[pt & 1][0];
    const __hip_bfloat16* Vb = &Vlds[pt & 1][0];

#pragma unroll
    for (int sc = 0; sc < 2; sc++) {
      const int kts = pt * 2 + sc;
      if (kts > lastt) break;              // block-uniform
      const bool act0 = (kts <= qtab[0]);

      // S^T = K Q^T for both halves (kf loads shared, issued in consumption order)
      f32x4 st1[4], st0[4];
#pragma unroll
      for (int ns = 0; ns < 4; ns++) {
        st1[ns] = (f32x4){0.f, 0.f, 0.f, 0.f};
        st0[ns] = (f32x4){0.f, 0.f, 0.f, 0.f};
      }
#pragma unroll
      for (int kk = 0; kk < 2; kk++) {
        bf16x8 kf[4];
#pragma unroll
        for (int ns = 0; ns < 4; ns++) {
          int row = sc * 64 + ns * 16 + fm;
          kf[ns] = *(const bf16x8*)(Kb + row * 64 + (((kk * 4 + g4) ^ (fm & 7)) << 3));
        }
#pragma unroll
        for (int ns = 0; ns < 4; ns++)
          st1[ns] = __builtin_amdgcn_mfma_f32_16x16x32_bf16(kf[ns], qf[1][kk], st1[ns], 0, 0, 0);
        if (act0)
#pragma unroll
          for (int ns = 0; ns < 4; ns++)
            st0[ns] = __builtin_amdgcn_mfma_f32_16x16x32_bf16(kf[ns], qf[0][kk], st0[ns], 0, 0, 0);
      }

      // V B-fragments for K=16 MFMA (after QK; shared by both halves)
      bf16x4 vf[4][4];   // [dd][ns]
#pragma unroll
      for (int dd = 0; dd < 4; dd++)
#pragma unroll
        for (int ns = 0; ns < 4; ns++) {
          int ch = sc * 8 + ns * 2 + (g4 >> 1);
          vf[dd][ns] = *(const bf16x4*)(Vb + (dd * 16 + fm) * 128 +
                                        ((ch ^ (fm & 7)) << 3) + (g4 & 1) * 4);
        }

      // per half: exp2 -> truncate-pack (v_perm) -> PV + rowsum MFMAs, all in regs
      auto half = [&](const f32x4 (&st)[4], int hh) {
        const bool diag = (kts == qtab[hh]);
#pragma unroll
        for (int ns = 0; ns < 4; ns++) {
          float e[4];
#pragma unroll
          for (int r = 0; r < 4; r++) {
            float p = __builtin_amdgcn_exp2f(st[ns][r]);
            if (diag) {
              int ktl = ns * 16 + g4 * 4 + r;
              p = (ktl > w * 16 + fm) ? 0.f : p;
            }
            e[r] = p;
          }
          unsigned lo = __builtin_amdgcn_perm(__builtin_bit_cast(unsigned, e[1]),
                                              __builtin_bit_cast(unsigned, e[0]), 0x07060302u);
          unsigned hi = __builtin_amdgcn_perm(__builtin_bit_cast(unsigned, e[3]),
                                              __builtin_bit_cast(unsigned, e[2]), 0x07060302u);
          uint2 pp; pp.x = lo; pp.y = hi;
          bf16x4 pf = __builtin_bit_cast(bf16x4, pp);
          lacc[hh] = __builtin_amdgcn_mfma_f32_16x16x16bf16_1k(pf, ones4, lacc[hh], 0, 0, 0);
#pragma unroll
          for (int dd = 0; dd < 4; dd++)
            acc[hh][dd] = __builtin_amdgcn_mfma_f32_16x16x16bf16_1k(pf, vf[dd][ns], acc[hh][dd], 0, 0, 0);
        }
      };
      half(st1, 1);
      if (act0) half(st0, 0);
    }
  }

  // epilogue: ctx = acc * rcp(l)
#pragma unroll
  for (int hh = 0; hh < 2; hh++) {
    float rl[4];
#pragma unroll
    for (int r = 0; r < 4; r++) rl[r] = __builtin_amdgcn_rcpf(lacc[hh][r]);
#pragma unroll
    for (int dd = 0; dd < 4; dd++)
#pragma unroll
      for (int r = 0; r < 4; r++) {
        int q = qtab[hh] * 64 + w * 16 + g4 * 4 + r;
        ctx[(rowb + q) * 1024 + h * 64 + dd * 16 + fm] =
            __float2bfloat16(acc[hh][dd][r] * rl[r]);
      }
  }
}

// ---------------- launch ----------------
extern "C" void kernel_launch(void* const* d_in, const int* in_sizes, int n_in,
                              void* d_out, int out_size, void* d_ws, size_t ws_size,
                              hipStream_t stream) {
  const float* x  = (const float*)d_in[0];
  const float* Wq = (const float*)d_in[1];
  const float* Wk = (const float*)d_in[2];
  const float* Wv = (const float*)d_in[3];
  const float* Wo = (const float*)d_in[4];
  const float* bo = (const float*)d_in[5];
  float* out = (float*)d_out;

  char* ws = (char*)d_ws;
  __hip_bfloat16* xb     = (__hip_bfloat16*)(ws);                      // 8 MiB (reused as Vt)
  __hip_bfloat16* Wqkv_t = (__hip_bfloat16*)(ws + (8ull  << 20));      // 6 MiB
  __hip_bfloat16* Wo_t   = (__hip_bfloat16*)(ws + (14ull << 20));      // 2 MiB
  __hip_bfloat16* QKV    = (__hip_bfloat16*)(ws + (16ull << 20));      // 24 MiB
  __hip_bfloat16* ctxb   = (__hip_bfloat16*)(ws + (40ull << 20));      // 8 MiB
  __hip_bfloat16* Vt     = xb;  // xb dead after QKV GEMM; reuse

  cvt_x<<<dim3(MROWS * DMODEL / (256 * 4)), dim3(256), 0, stream>>>(x, xb);
  trans_w<<<dim3(32, 32, 4), dim3(256), 0, stream>>>(Wq, Wk, Wv, Wo, Wqkv_t, Wo_t);
  gemm_kernel<128, true, 3><<<dim3(24, 32), dim3(256), 0, stream>>>(xb, Wqkv_t, (void*)QKV, nullptr, 3072);
  trans_v<<<dim3(32, 32), dim3(256), 0, stream>>>(QKV, Vt);
  attn_kernel<<<dim3(16, 32), dim3(256), 0, stream>>>(QKV, Vt, ctxb);
  gemm_kernel<64, false, 2><<<dim3(16, 32), dim3(256), 0, stream>>>(ctxb, Wo_t, (void*)out, bo, 1024);
}

// Round 11
// 167.336 us; speedup vs baseline: 1.1357x; 1.0493x over previous
//
#include <hip/hip_runtime.h>
#include <hip/hip_bf16.h>
#include <stdint.h>

#define SEQ    2048
#define BATCH  2
#define DMODEL 1024
#define NHEADS 16
#define HDIM   64
#define MROWS  (BATCH*SEQ)   // 4096

typedef __attribute__((ext_vector_type(8))) short bf16x8;
typedef __attribute__((ext_vector_type(4))) short bf16x4;
typedef __attribute__((ext_vector_type(4))) float f32x4;

__device__ inline void global_to_lds16(const void* g, void* l) {
  __builtin_amdgcn_global_load_lds(
      (const __attribute__((address_space(1))) uint32_t*)g,
      (__attribute__((address_space(3))) uint32_t*)l, 16, 0, 0);
}

__device__ inline unsigned short f2bf_bits(float f) {
  __hip_bfloat16 h = __float2bfloat16(f);
  return *(unsigned short*)&h;
}

// ---------------- x -> bf16 ----------------
__global__ void cvt_x(const float* __restrict__ x, __hip_bfloat16* __restrict__ xb) {
  int i = (blockIdx.x * 256 + threadIdx.x) * 4;
  float4 v = *(const float4*)(x + i);
  ushort4 o;
  o.x = f2bf_bits(v.x); o.y = f2bf_bits(v.y);
  o.z = f2bf_bits(v.z); o.w = f2bf_bits(v.w);
  *(ushort4*)(xb + i) = o;
}

// ------- W [k][n] f32 -> Wt [n][k] bf16 (tiled transpose) -------
__global__ void trans_w(const float* __restrict__ Wq, const float* __restrict__ Wk,
                        const float* __restrict__ Wv, const float* __restrict__ Wo,
                        __hip_bfloat16* __restrict__ Wqkv_t, __hip_bfloat16* __restrict__ Wo_t) {
  __shared__ float tile[32][33];
  int z = blockIdx.z;
  const float* W = (z == 0) ? Wq : (z == 1) ? Wk : (z == 2) ? Wv : Wo;
  __hip_bfloat16* dst = (z < 3) ? (Wqkv_t + (size_t)z * 1024 * 1024) : Wo_t;
  int k0 = blockIdx.x * 32, n0 = blockIdx.y * 32;
  int tx = threadIdx.x & 31, ty = threadIdx.x >> 5;
#pragma unroll
  for (int r = 0; r < 4; r++)
    tile[ty + r * 8][tx] = W[(size_t)(k0 + ty + r * 8) * 1024 + n0 + tx];
  __syncthreads();
#pragma unroll
  for (int r = 0; r < 4; r++)
    dst[(size_t)(n0 + ty + r * 8) * 1024 + k0 + tx] = __float2bfloat16(tile[tx][ty + r * 8]);
}

// ------ GEMM: C[M][ldc] = A[M][1024]*Wt[N][1024]^T (+bias), BK=64, swizzled LDS ------
// FUSE_VT: for n >= 2048 (V projection) write transposed into Vt[bh][d][s] instead of C.
template <int TN, bool OUT_BF16, int MINW, bool FUSE_VT>
__global__ __launch_bounds__(256, MINW)
void gemm_kernel(const __hip_bfloat16* __restrict__ A, const __hip_bfloat16* __restrict__ Bt,
                 void* __restrict__ C, const float* __restrict__ bias, int ldc,
                 __hip_bfloat16* __restrict__ Vt) {
  __shared__ __hip_bfloat16 Asl[128 * 64];
  __shared__ __hip_bfloat16 Bsl[TN * 64];

  const int t = threadIdx.x;
  const int lane = t & 63;
  const int w = t >> 6;
  constexpr int MI = (TN == 128) ? 4 : 2;
  const int wrow = (TN == 128) ? (w >> 1) * 64 : w * 32;
  const int wcol = (TN == 128) ? (w & 1) * 64 : 0;
  const int m0 = blockIdx.y * 128;
  const int n0 = blockIdx.x * TN;

  f32x4 acc[MI][4];
#pragma unroll
  for (int i = 0; i < MI; i++)
#pragma unroll
    for (int j = 0; j < 4; j++) acc[i][j] = (f32x4){0.f, 0.f, 0.f, 0.f};

  const int srow = lane >> 3;
  const int sjc = (lane & 7) ^ srow;
  const int fm = lane & 15;
  const int g4 = lane >> 4;

  for (int k0 = 0; k0 < 1024; k0 += 64) {
#pragma unroll
    for (int i = 0; i < 4; i++) {
      int seg = i * 4 + w;
      int r = seg * 8 + srow;
      global_to_lds16(A + (size_t)(m0 + r) * 1024 + k0 + sjc * 8,
                      (void*)(Asl + seg * 512 + lane * 8));
    }
#pragma unroll
    for (int i = 0; i < TN / 32; i++) {
      int seg = i * 4 + w;
      int r = seg * 8 + srow;
      global_to_lds16(Bt + (size_t)(n0 + r) * 1024 + k0 + sjc * 8,
                      (void*)(Bsl + seg * 512 + lane * 8));
    }
    __syncthreads();
#pragma unroll
    for (int kb = 0; kb < 2; kb++) {
      bf16x8 af[MI], bfr[4];
#pragma unroll
      for (int mi = 0; mi < MI; mi++) {
        int row = wrow + mi * 16 + fm;
        af[mi] = *(const bf16x8*)(Asl + row * 64 + (((kb * 4 + g4) ^ (row & 7)) << 3));
      }
#pragma unroll
      for (int ni = 0; ni < 4; ni++) {
        int row = wcol + ni * 16 + fm;
        bfr[ni] = *(const bf16x8*)(Bsl + row * 64 + (((kb * 4 + g4) ^ (row & 7)) << 3));
      }
#pragma unroll
      for (int mi = 0; mi < MI; mi++)
#pragma unroll
        for (int ni = 0; ni < 4; ni++)
          acc[mi][ni] = __builtin_amdgcn_mfma_f32_16x16x32_bf16(af[mi], bfr[ni], acc[mi][ni], 0, 0, 0);
    }
    __syncthreads();
  }

  const bool vt_block = FUSE_VT && (n0 >= 2048);
#pragma unroll
  for (int mi = 0; mi < MI; mi++) {
    int mb = m0 + wrow + mi * 16 + g4 * 4;
#pragma unroll
    for (int ni = 0; ni < 4; ni++) {
      int n = n0 + wcol + ni * 16 + fm;
      if (vt_block) {
        // V^T write: bh = b*16 + head, d = (n-2048)%64, s consecutive over r
        int nv = n - 2048;
        int bhh = (mb >> 11) * 16 + (nv >> 6);
        int d = nv & 63;
        int s = mb & 2047;
        unsigned short u[4];
#pragma unroll
        for (int r = 0; r < 4; r++) u[r] = f2bf_bits(acc[mi][ni][r]);
        *(ushort4*)(Vt + ((size_t)bhh * 64 + d) * 2048 + s) = *(const ushort4*)u;
      } else {
        float bv = OUT_BF16 ? 0.f : bias[n];
#pragma unroll
        for (int r = 0; r < 4; r++) {
          if (OUT_BF16)
            ((__hip_bfloat16*)C)[(size_t)(mb + r) * ldc + n] = __float2bfloat16(acc[mi][ni][r]);
          else
            ((float*)C)[(size_t)(mb + r) * ldc + n] = acc[mi][ni][r] + bv;
        }
      }
    }
  }
}

// ---- causal flash attention: XCD-grouped 1D grid, paired q-tiles, 128-kt dbuf ----
// Assuming XCD = wgid%8 round-robin: each XCD owns 4 bh values (16 blocks each), so
// its K/V working set is 2MB < 4MB L2 -> staging at L2 latency, covered by prefetch.
// Co-resident blocks (k, k+32 within XCD) get complementary jb (uniform tile counts).
__global__ __launch_bounds__(256, 2)
void attn_kernel(const __hip_bfloat16* __restrict__ QKV,
                 const __hip_bfloat16* __restrict__ Vt,
                 __hip_bfloat16* __restrict__ ctx) {
  __shared__ __hip_bfloat16 Klds[2][128 * 64];   // [buf][kt][d], chunk j at slot j^(row&7)
  __shared__ __hip_bfloat16 Vlds[2][64 * 128];   // [buf][d][kt], chunk j at slot j^(d&7)

  const int t = threadIdx.x;
  const int lane = t & 63;
  const int w = t >> 6;                    // 0..3
  const int L = blockIdx.x;                // 0..511
  const int bh = (L & 7) + 8 * ((L >> 3) & 3);   // XCD-local bh group
  const int jraw = L >> 5;                       // 0..15
  const int jb = (jraw < 8) ? jraw : 23 - jraw;  // co-resident complementary pairs
  const int qtab[2] = { jb, 31 - jb };
  const int b = bh >> 4, h = bh & 15;
  const int fm = lane & 15;
  const int g4 = lane >> 4;
  const int fk = g4 * 8;
  const size_t rowb = (size_t)b * SEQ;
  const float c = 0.18033688011112042f;    // log2(e)/8

  const int krr = lane >> 3;               // 0..7
  const int kjc = (lane & 7) ^ krr;        // K staging swizzle
  const int vrr = lane >> 4;               // 0..3

  // Q fragments (MFMA B operands), prescaled by c
  bf16x8 qf[2][2];
#pragma unroll
  for (int hh = 0; hh < 2; hh++) {
    const __hip_bfloat16* qp = QKV + (rowb + qtab[hh] * 64 + w * 16 + fm) * 3072 + h * 64 + fk;
    bf16x8 r0 = *(const bf16x8*)qp;
    bf16x8 r1 = *(const bf16x8*)(qp + 32);
#pragma unroll
    for (int i = 0; i < 8; i++) {
      float f0 = __uint_as_float(((unsigned)(unsigned short)r0[i]) << 16) * c;
      float f1 = __uint_as_float(((unsigned)(unsigned short)r1[i]) << 16) * c;
      r0[i] = (short)f2bf_bits(f0);
      r1[i] = (short)f2bf_bits(f1);
    }
    qf[hh][0] = r0; qf[hh][1] = r1;
  }

  bf16x4 ones4;
#pragma unroll
  for (int i = 0; i < 4; i++) ones4[i] = (short)0x3F80;

  f32x4 acc[2][4];
  f32x4 lacc[2];
#pragma unroll
  for (int hh = 0; hh < 2; hh++) {
    lacc[hh] = (f32x4){0.f, 0.f, 0.f, 0.f};
#pragma unroll
    for (int d = 0; d < 4; d++) acc[hh][d] = (f32x4){0.f, 0.f, 0.f, 0.f};
  }

  // stage one 128-kt phase: K 16KB + V 16KB
  auto stage = [&](int pt, int bufi) {
    const int kt0 = pt * 128;
#pragma unroll
    for (int i = 0; i < 4; i++) {
      int seg = i * 4 + w;                 // 0..15
      int kr = seg * 8 + krr;              // K row 0..127
      global_to_lds16(QKV + (rowb + kt0 + kr) * 3072 + 1024 + h * 64 + kjc * 8,
                      (void*)(&Klds[bufi][0] + seg * 512 + lane * 8));
      int vd = seg * 4 + vrr;              // Vt d-row 0..63
      int vjc = (lane & 15) ^ ((seg & 1) * 4 + vrr);
      global_to_lds16(Vt + ((size_t)bh * 64 + vd) * 2048 + kt0 + vjc * 8,
                      (void*)(&Vlds[bufi][0] + seg * 512 + lane * 8));
    }
  };

  const int lastt = qtab[1];               // 16..31
  const int lastp = lastt >> 1;
  stage(0, 0);
  for (int pt = 0; pt <= lastp; ++pt) {
    __syncthreads();
    if (pt < lastp) stage(pt + 1, (pt + 1) & 1);
    const __hip_bfloat16* Kb = &Klds[pt & 1][0];
    const __hip_bfloat16* Vb = &Vlds[pt & 1][0];

#pragma unroll
    for (int sc = 0; sc < 2; sc++) {
      const int kts = pt * 2 + sc;
      if (kts > lastt) break;
      const bool act0 = (kts <= qtab[0]);

      // S^T = K Q^T for both halves (kf loads shared, consumption order)
      f32x4 st1[4], st0[4];
#pragma unroll
      for (int ns = 0; ns < 4; ns++) {
        st1[ns] = (f32x4){0.f, 0.f, 0.f, 0.f};
        st0[ns] = (f32x4){0.f, 0.f, 0.f, 0.f};
      }
#pragma unroll
      for (int kk = 0; kk < 2; kk++) {
        bf16x8 kf[4];
#pragma unroll
        for (int ns = 0; ns < 4; ns++) {
          int row = sc * 64 + ns * 16 + fm;
          kf[ns] = *(const bf16x8*)(Kb + row * 64 + (((kk * 4 + g4) ^ (fm & 7)) << 3));
        }
#pragma unroll
        for (int ns = 0; ns < 4; ns++)
          st1[ns] = __builtin_amdgcn_mfma_f32_16x16x32_bf16(kf[ns], qf[1][kk], st1[ns], 0, 0, 0);
        if (act0)
#pragma unroll
          for (int ns = 0; ns < 4; ns++)
            st0[ns] = __builtin_amdgcn_mfma_f32_16x16x32_bf16(kf[ns], qf[0][kk], st0[ns], 0, 0, 0);
      }

      // V B-fragments for K=16 MFMA (after QK; shared by both halves)
      bf16x4 vf[4][4];
#pragma unroll
      for (int dd = 0; dd < 4; dd++)
#pragma unroll
        for (int ns = 0; ns < 4; ns++) {
          int ch = sc * 8 + ns * 2 + (g4 >> 1);
          vf[dd][ns] = *(const bf16x4*)(Vb + (dd * 16 + fm) * 128 +
                                        ((ch ^ (fm & 7)) << 3) + (g4 & 1) * 4);
        }

      auto half = [&](const f32x4 (&st)[4], int hh) {
        const bool diag = (kts == qtab[hh]);
#pragma unroll
        for (int ns = 0; ns < 4; ns++) {
          float e[4];
#pragma unroll
          for (int r = 0; r < 4; r++) {
            float p = __builtin_amdgcn_exp2f(st[ns][r]);
            if (diag) {
              int ktl = ns * 16 + g4 * 4 + r;
              p = (ktl > w * 16 + fm) ? 0.f : p;
            }
            e[r] = p;
          }
          unsigned lo = __builtin_amdgcn_perm(__builtin_bit_cast(unsigned, e[1]),
                                              __builtin_bit_cast(unsigned, e[0]), 0x07060302u);
          unsigned hi = __builtin_amdgcn_perm(__builtin_bit_cast(unsigned, e[3]),
                                              __builtin_bit_cast(unsigned, e[2]), 0x07060302u);
          uint2 pp; pp.x = lo; pp.y = hi;
          bf16x4 pf = __builtin_bit_cast(bf16x4, pp);
          lacc[hh] = __builtin_amdgcn_mfma_f32_16x16x16bf16_1k(pf, ones4, lacc[hh], 0, 0, 0);
#pragma unroll
          for (int dd = 0; dd < 4; dd++)
            acc[hh][dd] = __builtin_amdgcn_mfma_f32_16x16x16bf16_1k(pf, vf[dd][ns], acc[hh][dd], 0, 0, 0);
        }
      };
      half(st1, 1);
      if (act0) half(st0, 0);
    }
  }

  // epilogue: ctx = acc * rcp(l)
#pragma unroll
  for (int hh = 0; hh < 2; hh++) {
    float rl[4];
#pragma unroll
    for (int r = 0; r < 4; r++) rl[r] = __builtin_amdgcn_rcpf(lacc[hh][r]);
#pragma unroll
    for (int dd = 0; dd < 4; dd++)
#pragma unroll
      for (int r = 0; r < 4; r++) {
        int q = qtab[hh] * 64 + w * 16 + g4 * 4 + r;
        ctx[(rowb + q) * 1024 + h * 64 + dd * 16 + fm] =
            __float2bfloat16(acc[hh][dd][r] * rl[r]);
      }
  }
}

// ---------------- launch ----------------
extern "C" void kernel_launch(void* const* d_in, const int* in_sizes, int n_in,
                              void* d_out, int out_size, void* d_ws, size_t ws_size,
                              hipStream_t stream) {
  const float* x  = (const float*)d_in[0];
  const float* Wq = (const float*)d_in[1];
  const float* Wk = (const float*)d_in[2];
  const float* Wv = (const float*)d_in[3];
  const float* Wo = (const float*)d_in[4];
  const float* bo = (const float*)d_in[5];
  float* out = (float*)d_out;

  char* ws = (char*)d_ws;
  __hip_bfloat16* xb     = (__hip_bfloat16*)(ws);                      // 8 MiB
  __hip_bfloat16* Wqkv_t = (__hip_bfloat16*)(ws + (8ull  << 20));      // 6 MiB
  __hip_bfloat16* Wo_t   = (__hip_bfloat16*)(ws + (14ull << 20));      // 2 MiB
  __hip_bfloat16* QKV    = (__hip_bfloat16*)(ws + (16ull << 20));      // 24 MiB (V cols unused)
  __hip_bfloat16* ctxb   = (__hip_bfloat16*)(ws + (40ull << 20));      // 8 MiB
  __hip_bfloat16* Vt     = (__hip_bfloat16*)(ws + (48ull << 20));      // 8 MiB

  cvt_x<<<dim3(MROWS * DMODEL / (256 * 4)), dim3(256), 0, stream>>>(x, xb);
  trans_w<<<dim3(32, 32, 4), dim3(256), 0, stream>>>(Wq, Wk, Wv, Wo, Wqkv_t, Wo_t);
  gemm_kernel<128, true, 3, true><<<dim3(24, 32), dim3(256), 0, stream>>>(
      xb, Wqkv_t, (void*)QKV, nullptr, 3072, Vt);
  attn_kernel<<<dim3(512), dim3(256), 0, stream>>>(QKV, Vt, ctxb);
  gemm_kernel<64, false, 2, false><<<dim3(16, 32), dim3(256), 0, stream>>>(
      ctxb, Wo_t, (void*)out, bo, 1024, nullptr);
}